// Round 2
// baseline (148.382 us; speedup 1.0000x reference)
//
#include <hip/hip_runtime.h>
#include <stdint.h>

#define S_LEN 4096
#define NH    16
#define HD    64
#define RSTR  (NH * HD)   // seq-row stride in floats

typedef __attribute__((ext_vector_type(8))) __bf16 bf16x8;
typedef __attribute__((ext_vector_type(4))) short short4v;
typedef __attribute__((ext_vector_type(4))) float floatx4;

union BF4 { unsigned short u[4]; unsigned d[2]; short4v s; };

// pack two f32 -> bf16x2 (round-half-up) in one v_perm_b32
__device__ __forceinline__ unsigned pkbf(float a, float b) {
    unsigned ua = __builtin_bit_cast(unsigned, a) + 0x8000u;
    unsigned ub = __builtin_bit_cast(unsigned, b) + 0x8000u;
    return __builtin_amdgcn_perm(ub, ua, 0x07060302u);
}

__device__ __forceinline__ floatx4 mfma16(short4v a, short4v b, floatx4 c) {
#if __has_builtin(__builtin_amdgcn_mfma_f32_16x16x16bf16_1k)
    return __builtin_amdgcn_mfma_f32_16x16x16bf16_1k(a, b, c, 0, 0, 0);
#else
    floatx4 d;
    asm volatile("v_mfma_f32_16x16x16_bf16 %0, %1, %2, %3\n\ts_nop 7\n\ts_nop 7"
                 : "=v"(d) : "v"(a), "v"(b), "v"(c));
    return d;
#endif
}

// async global->LDS, 16B/lane
__device__ __forceinline__ void gl16(const void* g, void* l) {
#if __has_builtin(__builtin_amdgcn_global_load_lds)
    __builtin_amdgcn_global_load_lds((const __attribute__((address_space(1))) unsigned int*)g,
                                     (__attribute__((address_space(3))) unsigned int*)l, 16, 0, 0);
#else
    *(uint4*)l = *(const uint4*)g;
#endif
}

// ---------------- preprocess: K -> bf16 swizzled tiles, V -> V^T bf16 swizzled tiles
// tile(h,tau) = 64x64 bf16 = 8 KB, contiguous; element (r, c) at
// r*64 + ((c>>3)^(r&7))*8 + (c&7)  (XOR granule swizzle)
// R2 change: V^T gather now goes through an LDS transpose — global side is
// coalesced float4 row loads (was 16 scalar loads at 4KB stride / thread).
__global__ __launch_bounds__(256)
void pp_kv(const float* __restrict__ K, const float* __restrict__ V,
           unsigned short* __restrict__ Kz, unsigned short* __restrict__ Vz) {
    __shared__ __align__(16) float vt[64][68];   // +4 pad: 16B-aligned rows, read conflict-free
    const int bid = blockIdx.x;
    const int h   = bid & 15;
    const int tau = bid >> 4;
    const int tid = threadIdx.x;
    // K: thread (r = tid>>2, gg = tid&3) covers d = 16gg..16gg+15 of row r
    {
        const int r = tid >> 2, gg = tid & 3;
        const float* kp = K + ((size_t)(64 * tau + r) * NH + h) * HD + 16 * gg;
        const float4 a = *reinterpret_cast<const float4*>(kp);
        const float4 b = *reinterpret_cast<const float4*>(kp + 4);
        const float4 c = *reinterpret_cast<const float4*>(kp + 8);
        const float4 d = *reinterpret_cast<const float4*>(kp + 12);
        uint4 f0, f1;
        f0.x = pkbf(a.x, a.y); f0.y = pkbf(a.z, a.w);
        f0.z = pkbf(b.x, b.y); f0.w = pkbf(b.z, b.w);
        f1.x = pkbf(c.x, c.y); f1.y = pkbf(c.z, c.w);
        f1.z = pkbf(d.x, d.y); f1.w = pkbf(d.z, d.w);
        unsigned short* out = Kz + ((size_t)(h * 64 + tau)) * 4096 + r * 64;
        *reinterpret_cast<uint4*>(out + (((2 * gg)     ^ (r & 7)) * 8)) = f0;
        *reinterpret_cast<uint4*>(out + (((2 * gg + 1) ^ (r & 7)) * 8)) = f1;
    }
    // V: coalesced row loads -> LDS
    {
        const int r = tid >> 2, ch = tid & 3;
        const float* vrow = V + ((size_t)(64 * tau + r) * NH + h) * HD + 4 * ch;
        #pragma unroll
        for (int k2 = 0; k2 < 4; ++k2)
            *reinterpret_cast<float4*>(&vt[r][4 * ch + 16 * k2]) =
                *reinterpret_cast<const float4*>(vrow + 16 * k2);
    }
    __syncthreads();
    // V^T: thread (dr = tid&63, kg = tid>>6) covers kv = 16kg..16kg+15 at d = dr
    {
        const int dr = tid & 63, kg = tid >> 6;
        float x[16];
        #pragma unroll
        for (int j = 0; j < 16; ++j) x[j] = vt[16 * kg + j][dr];
        uint4 g0, g1;
        g0.x = pkbf(x[0],  x[1]);  g0.y = pkbf(x[2],  x[3]);
        g0.z = pkbf(x[4],  x[5]);  g0.w = pkbf(x[6],  x[7]);
        g1.x = pkbf(x[8],  x[9]);  g1.y = pkbf(x[10], x[11]);
        g1.z = pkbf(x[12], x[13]); g1.w = pkbf(x[14], x[15]);
        unsigned short* out = Vz + ((size_t)(h * 64 + tau)) * 4096 + dr * 64;
        *reinterpret_cast<uint4*>(out + (((2 * kg)     ^ (dr & 7)) * 8)) = g0;
        *reinterpret_cast<uint4*>(out + (((2 * kg + 1) ^ (dr & 7)) * 8)) = g1;
    }
}

// ---------------- main kernel
// R2 change: wave split 4xKV -> 2Q x 2KV hybrid. acc 64->32 regs (register
// file was THE occupancy cap: 76+64=140 -> 3 waves/SIMD). Now ~70+32 ≈ 102
// -> 4 waves/SIMD, LDS 40KB->32KB (Qlds is a prologue overlay on K buf1),
// epilogue is a single 2-wave LDS reduction. MFMA/exp2 work per wave
// unchanged; LDS reads double to 128B/lane/iter (still under CU LDS BW).
__global__ __launch_bounds__(256, 4)
void fa_main(const float* __restrict__ Q, const unsigned short* __restrict__ Kz,
             const unsigned short* __restrict__ Vz, const int* __restrict__ causal_p,
             float* __restrict__ O) {
    __shared__ __align__(16) unsigned char smem[32768];
    unsigned short* Klds = (unsigned short*)smem;              // 2 x 8 KB dbuf
    unsigned short* Vlds = (unsigned short*)(smem + 16384);    // 2 x 8 KB dbuf
    unsigned short* Qlds = (unsigned short*)(smem + 8192);     // prologue overlay on K buf1
    float* Lred = (float*)smem;                                // epilogue overlay, 18432 B
    float* Lsum = (float*)(smem + 18432);                      // epilogue overlay, 512 B

    const int bid = blockIdx.x;
    const int h   = bid & 15;
    const int x   = 63 - (bid >> 4);       // longest-first dispatch order (LPT)
    const int q0  = x * 64;

    const int tid = threadIdx.x;
    const int wv  = tid >> 6;
    const int wq  = wv & 1;                // q-half owned by this wave
    const int wk  = wv >> 1;               // kv-half owned by this wave
    const int ln  = tid & 63;
    const int c16 = ln & 15;
    const int qd  = ln >> 4;
    const int causal = causal_p[0];

    const float SC = 0.18033688011112042f;  // (1/sqrt(64)) * log2(e)

    // ---- stage Q tile (scaled fp32->bf16, swizzled) into K-buf1 overlay ----
    {
        const int r = tid >> 2, gg = tid & 3;
        const float* qp = Q + ((size_t)(q0 + r) * NH + h) * HD + 16 * gg;
        const float4 a = *reinterpret_cast<const float4*>(qp);
        const float4 b = *reinterpret_cast<const float4*>(qp + 4);
        const float4 c = *reinterpret_cast<const float4*>(qp + 8);
        const float4 d = *reinterpret_cast<const float4*>(qp + 12);
        uint4 f0, f1;
        f0.x = pkbf(a.x * SC, a.y * SC); f0.y = pkbf(a.z * SC, a.w * SC);
        f0.z = pkbf(b.x * SC, b.y * SC); f0.w = pkbf(b.z * SC, b.w * SC);
        f1.x = pkbf(c.x * SC, c.y * SC); f1.y = pkbf(c.z * SC, c.w * SC);
        f1.z = pkbf(d.x * SC, d.y * SC); f1.w = pkbf(d.z * SC, d.w * SC);
        unsigned short* out = Qlds + r * 64;
        *reinterpret_cast<uint4*>(out + (((2 * gg)     ^ (r & 7)) * 8)) = f0;
        *reinterpret_cast<uint4*>(out + (((2 * gg + 1) ^ (r & 7)) * 8)) = f1;
    }

    // glds pointers (per-lane; lane0 value is the wave-uniform LDS base)
    const char* kg = (const char*)Kz + (size_t)h * 64 * 8192 + wv * 2048 + ln * 16;
    const char* vg = (const char*)Vz + (size_t)h * 64 * 8192 + wv * 2048 + ln * 16;
    char* kl = (char*)smem + wv * 2048 + ln * 16;
    char* vl = (char*)smem + 16384 + wv * 2048 + ln * 16;

#define GLDS_TILE(IT, BUF) do {                                  \
    const char* ks_ = kg + (size_t)(IT) * 8192;                  \
    const char* vs_ = vg + (size_t)(IT) * 8192;                  \
    char* kd_ = kl + (BUF) * 8192;                               \
    char* vd_ = vl + (BUF) * 8192;                               \
    gl16(ks_, kd_); gl16(ks_ + 1024, kd_ + 1024);                \
    gl16(vs_, vd_); gl16(vs_ + 1024, vd_ + 1024);                \
} while (0)

    const int nIter = causal ? (x + 1) : (S_LEN / 64);

    floatx4 acc[4][2];   // [md (d-tile)][t_l (q-tile in wq half)], partial O^T over wk's kv
    #pragma unroll
    for (int m = 0; m < 4; ++m)
        #pragma unroll
        for (int t = 0; t < 2; ++t) acc[m][t] = floatx4{0.f, 0.f, 0.f, 0.f};
    float lacc[2] = {0.f, 0.f};

    const int e7 = c16 & 7;
    const int o0 = (qd ^ e7) * 8;              // elems, x32 frag chunk 0
    const int o1 = ((4 + qd) ^ e7) * 8;        // elems, x32 frag chunk 1
    // V^T b64 frag offsets for kv sub-tiles ks=0,1 of this wave's kv half
    const int vo0 = ((4 * wk + 0 + (qd >> 1)) ^ e7) * 8 + (qd & 1) * 4;
    const int vo1 = ((4 * wk + 2 + (qd >> 1)) ^ e7) * 8 + (qd & 1) * 4;

    GLDS_TILE(0, 0);
    __syncthreads();   // Q staged + tile0 loaded (drains lgkm + vm)

    // ---- hoist loop-invariant Q fragments (this wave's 32 q rows, 16 VGPR) ----
    bf16x8 qh0[2], qh1[2];
    #pragma unroll
    for (int t = 0; t < 2; ++t) {
        const unsigned short* qrow = Qlds + (16 * (2 * wq + t) + c16) * 64;
        qh0[t] = *reinterpret_cast<const bf16x8*>(qrow + o0);
        qh1[t] = *reinterpret_cast<const bf16x8*>(qrow + o1);
    }
    __syncthreads();   // all waves done hoisting before iter0 prefetch hits K buf1

    int cur = 0;
    for (int it = 0; it < nIter; ++it) {
        if (it + 1 < nIter) GLDS_TILE(it + 1, cur ^ 1);

        const unsigned short* Kb = Klds + cur * 4096;
        const unsigned short* Vb = Vlds + cur * 4096;

        // K fragments: this wave's kv half, two 16-row sub-tiles
        bf16x8 kf0[2], kf1[2];
        #pragma unroll
        for (int ks = 0; ks < 2; ++ks) {
            const unsigned short* krow = Kb + (32 * wk + 16 * ks + c16) * 64;
            kf0[ks] = *reinterpret_cast<const bf16x8*>(krow + o0);
            kf1[ks] = *reinterpret_cast<const bf16x8*>(krow + o1);
        }

        const bool maskit = (causal != 0) && (it == nIter - 1);

        // S^T = K Q^T per (ks, t); exp2 -> P in B-layout for x16 PV
        BF4 pf[2][2];   // [ks][t]
        #pragma unroll
        for (int ks = 0; ks < 2; ++ks) {
            const int kvb = 32 * wk + 16 * ks + 4 * qd;   // kv-local of reg i=0
            #pragma unroll
            for (int t = 0; t < 2; ++t) {
                floatx4 st = __builtin_amdgcn_mfma_f32_16x16x32_bf16(
                    kf0[ks], qh0[t], floatx4{0.f, 0.f, 0.f, 0.f}, 0, 0, 0);
                st = __builtin_amdgcn_mfma_f32_16x16x32_bf16(kf1[ks], qh1[t], st, 0, 0, 0);
                const int qloc = 16 * (2 * wq + t) + c16;
                float p[4];
                #pragma unroll
                for (int i = 0; i < 4; ++i) {
                    float sv = st[i];
                    if (maskit && (kvb + i > qloc)) sv = -1e30f;
                    p[i] = __builtin_amdgcn_exp2f(sv);
                }
                lacc[t] += (p[0] + p[1]) + (p[2] + p[3]);
                pf[ks][t].d[0] = pkbf(p[0], p[1]);
                pf[ks][t].d[1] = pkbf(p[2], p[3]);
            }
        }

        // O^T(partial) += V^T[:, kv_wk] P^T[kv_wk, :]  (x16, k=16 per sub-tile)
        #pragma unroll
        for (int md = 0; md < 4; ++md) {
            const unsigned short* vrow = Vb + (16 * md + c16) * 64;
            BF4 vf0, vf1;
            *reinterpret_cast<uint2*>(&vf0.d[0]) = *reinterpret_cast<const uint2*>(vrow + vo0);
            *reinterpret_cast<uint2*>(&vf1.d[0]) = *reinterpret_cast<const uint2*>(vrow + vo1);
            #pragma unroll
            for (int t = 0; t < 2; ++t) {
                acc[md][t] = mfma16(vf0.s, pf[0][t].s, acc[md][t]);
                acc[md][t] = mfma16(vf1.s, pf[1][t].s, acc[md][t]);
            }
        }

        __syncthreads();   // drains glds (next buf ready) + protects buf reuse
        cur ^= 1;
    }

    // ---- epilogue: pairwise (wk=0 + wk=1) reduction via LDS ----
    // Lane (c16,qd) reg (md,t,i) holds O^T[d=16md+4qd+i][q=16(2wq+t)+c16] partial.
    #pragma unroll
    for (int t = 0; t < 2; ++t) {
        float lt = lacc[t];
        lt += __shfl_xor(lt, 16);
        lt += __shfl_xor(lt, 32);
        if (qd == 0) Lsum[wk * 64 + wq * 32 + t * 16 + c16] = lt;
    }
    if (wk == 0) {
        float* Lw = Lred + (wq * 64 + ln) * 36;
        #pragma unroll
        for (int md = 0; md < 4; ++md)
            #pragma unroll
            for (int t = 0; t < 2; ++t)
                *reinterpret_cast<floatx4*>(&Lw[(md * 2 + t) * 4]) = acc[md][t];
    }
    __syncthreads();
    if (wk == 1) {
        const float* Lr = Lred + (wq * 64 + ln) * 36;
        float inv[2];
        #pragma unroll
        for (int t = 0; t < 2; ++t) {
            const int qidx = wq * 32 + t * 16 + c16;
            inv[t] = 1.0f / (Lsum[qidx] + Lsum[64 + qidx]);
        }
        #pragma unroll
        for (int md = 0; md < 4; ++md)
            #pragma unroll
            for (int t = 0; t < 2; ++t) {
                const floatx4 b = *reinterpret_cast<const floatx4*>(&Lr[(md * 2 + t) * 4]);
                const floatx4 a = acc[md][t];
                floatx4 o;
                o[0] = (a[0] + b[0]) * inv[t];
                o[1] = (a[1] + b[1]) * inv[t];
                o[2] = (a[2] + b[2]) * inv[t];
                o[3] = (a[3] + b[3]) * inv[t];
                const int q = q0 + 16 * (2 * wq + t) + c16;
                *reinterpret_cast<floatx4*>(O + ((size_t)q * NH + h) * HD + 16 * md + 4 * qd) = o;
            }
    }
}

extern "C" void kernel_launch(void* const* d_in, const int* in_sizes, int n_in,
                              void* d_out, int out_size, void* d_ws, size_t ws_size,
                              hipStream_t stream) {
    const float* q = (const float*)d_in[0];
    const float* k = (const float*)d_in[1];
    const float* v = (const float*)d_in[2];
    const int* causal = (const int*)d_in[3];
    float* out = (float*)d_out;
    unsigned short* Kz = (unsigned short*)d_ws;                      // 8 MB
    unsigned short* Vz = Kz + (size_t)NH * 64 * 4096;                // 8 MB
    pp_kv<<<dim3(64 * NH), dim3(256), 0, stream>>>(k, v, Kz, Vz);
    fa_main<<<dim3(64 * NH), dim3(256), 0, stream>>>(q, Kz, Vz, causal, out);
}

// Round 3
// 142.250 us; speedup vs baseline: 1.0431x; 1.0431x over previous
//
#include <hip/hip_runtime.h>
#include <stdint.h>

#define S_LEN 4096
#define NH    16
#define HD    64
#define RSTR  (NH * HD)   // seq-row stride in floats

typedef __attribute__((ext_vector_type(8))) __bf16 bf16x8;
typedef __attribute__((ext_vector_type(4))) short short4v;
typedef __attribute__((ext_vector_type(4))) float floatx4;

union BF4 { unsigned short u[4]; unsigned d[2]; short4v s; };

// pack two f32 -> bf16x2 (round-half-up) in one v_perm_b32
__device__ __forceinline__ unsigned pkbf(float a, float b) {
    unsigned ua = __builtin_bit_cast(unsigned, a) + 0x8000u;
    unsigned ub = __builtin_bit_cast(unsigned, b) + 0x8000u;
    return __builtin_amdgcn_perm(ub, ua, 0x07060302u);
}

__device__ __forceinline__ floatx4 mfma16(short4v a, short4v b, floatx4 c) {
#if __has_builtin(__builtin_amdgcn_mfma_f32_16x16x16bf16_1k)
    return __builtin_amdgcn_mfma_f32_16x16x16bf16_1k(a, b, c, 0, 0, 0);
#else
    floatx4 d;
    asm volatile("v_mfma_f32_16x16x16_bf16 %0, %1, %2, %3\n\ts_nop 7\n\ts_nop 7"
                 : "=v"(d) : "v"(a), "v"(b), "v"(c));
    return d;
#endif
}

// async global->LDS, 16B/lane
__device__ __forceinline__ void gl16(const void* g, void* l) {
#if __has_builtin(__builtin_amdgcn_global_load_lds)
    __builtin_amdgcn_global_load_lds((const __attribute__((address_space(1))) unsigned int*)g,
                                     (__attribute__((address_space(3))) unsigned int*)l, 16, 0, 0);
#else
    *(uint4*)l = *(const uint4*)g;
#endif
}

// ---------------- preprocess: K -> bf16 swizzled tiles, V -> V^T bf16 swizzled tiles
// tile(h,tau) = 64x64 bf16 = 8 KB, contiguous; element (r, c) at
// r*64 + ((c>>3)^(r&7))*8 + (c&7)  (XOR granule swizzle)
__global__ __launch_bounds__(256)
void pp_kv(const float* __restrict__ K, const float* __restrict__ V,
           unsigned short* __restrict__ Kz, unsigned short* __restrict__ Vz) {
    __shared__ __align__(16) float vt[64][68];   // +4 pad: 16B-aligned rows, read conflict-free
    const int bid = blockIdx.x;
    const int h   = bid & 15;
    const int tau = bid >> 4;
    const int tid = threadIdx.x;
    // K: thread (r = tid>>2, gg = tid&3) covers d = 16gg..16gg+15 of row r
    {
        const int r = tid >> 2, gg = tid & 3;
        const float* kp = K + ((size_t)(64 * tau + r) * NH + h) * HD + 16 * gg;
        const float4 a = *reinterpret_cast<const float4*>(kp);
        const float4 b = *reinterpret_cast<const float4*>(kp + 4);
        const float4 c = *reinterpret_cast<const float4*>(kp + 8);
        const float4 d = *reinterpret_cast<const float4*>(kp + 12);
        uint4 f0, f1;
        f0.x = pkbf(a.x, a.y); f0.y = pkbf(a.z, a.w);
        f0.z = pkbf(b.x, b.y); f0.w = pkbf(b.z, b.w);
        f1.x = pkbf(c.x, c.y); f1.y = pkbf(c.z, c.w);
        f1.z = pkbf(d.x, d.y); f1.w = pkbf(d.z, d.w);
        unsigned short* out = Kz + ((size_t)(h * 64 + tau)) * 4096 + r * 64;
        *reinterpret_cast<uint4*>(out + (((2 * gg)     ^ (r & 7)) * 8)) = f0;
        *reinterpret_cast<uint4*>(out + (((2 * gg + 1) ^ (r & 7)) * 8)) = f1;
    }
    // V: coalesced row loads -> LDS
    {
        const int r = tid >> 2, ch = tid & 3;
        const float* vrow = V + ((size_t)(64 * tau + r) * NH + h) * HD + 4 * ch;
        #pragma unroll
        for (int k2 = 0; k2 < 4; ++k2)
            *reinterpret_cast<float4*>(&vt[r][4 * ch + 16 * k2]) =
                *reinterpret_cast<const float4*>(vrow + 16 * k2);
    }
    __syncthreads();
    // V^T: thread (dr = tid&63, kg = tid>>6) covers kv = 16kg..16kg+15 at d = dr
    {
        const int dr = tid & 63, kg = tid >> 6;
        float x[16];
        #pragma unroll
        for (int j = 0; j < 16; ++j) x[j] = vt[16 * kg + j][dr];
        uint4 g0, g1;
        g0.x = pkbf(x[0],  x[1]);  g0.y = pkbf(x[2],  x[3]);
        g0.z = pkbf(x[4],  x[5]);  g0.w = pkbf(x[6],  x[7]);
        g1.x = pkbf(x[8],  x[9]);  g1.y = pkbf(x[10], x[11]);
        g1.z = pkbf(x[12], x[13]); g1.w = pkbf(x[14], x[15]);
        unsigned short* out = Vz + ((size_t)(h * 64 + tau)) * 4096 + dr * 64;
        *reinterpret_cast<uint4*>(out + (((2 * kg)     ^ (dr & 7)) * 8)) = g0;
        *reinterpret_cast<uint4*>(out + (((2 * kg + 1) ^ (dr & 7)) * 8)) = g1;
    }
}

// ---------------- main kernel
// R3 change: break the per-iteration global->LDS round trip out of the
// critical path. The old loop issued GLDS(t+1) then __syncthreads() at iter
// end (= s_waitcnt vmcnt(0) + barrier), serializing a full memory latency
// into EVERY iteration (~1200 cyc/block-iter measured vs ~300 cyc of work).
// Now: 3-deep K/V buffers (48 KB), prefetch distance 2, and a counted
// s_waitcnt vmcnt(4) + raw s_barrier per iter (vmcnt(0) only on the last
// iter). Tiles t+1/t+2 stay in flight across the barrier.
// Safety: reads of buf[(t+2)%3] happen at iter t-1 and complete before
// barrier(t) (their MFMA consumers carry compiler lgkm waits); the GLDS
// issue for tile t+2 is placed AFTER barrier(t). Prologue __syncthreads
// drains vmcnt to exactly 0 at loop entry, so in-loop counts are exact
// (loop body has no other vmem ops).
__global__ __launch_bounds__(256, 3)
void fa_main(const float* __restrict__ Q, const unsigned short* __restrict__ Kz,
             const unsigned short* __restrict__ Vz, const int* __restrict__ causal_p,
             float* __restrict__ O) {
    __shared__ __align__(16) unsigned char smem[49152];
    unsigned short* Klds = (unsigned short*)smem;              // 3 x 8 KB
    unsigned short* Vlds = (unsigned short*)(smem + 24576);    // 3 x 8 KB
    unsigned short* Qlds = (unsigned short*)(smem + 16384);    // prologue overlay on K buf2
    float* Lred = (float*)smem;                                // epilogue overlay, 18432 B
    float* Lsum = (float*)(smem + 18432);                      // epilogue overlay, 512 B

    const int bid = blockIdx.x;
    const int h   = bid & 15;
    const int x   = 63 - (bid >> 4);       // longest-first dispatch order (LPT)
    const int q0  = x * 64;

    const int tid = threadIdx.x;
    const int wv  = tid >> 6;
    const int wq  = wv & 1;                // q-half owned by this wave
    const int wk  = wv >> 1;               // kv-half owned by this wave
    const int ln  = tid & 63;
    const int c16 = ln & 15;
    const int qd  = ln >> 4;
    const int causal = causal_p[0];

    const float SC = 0.18033688011112042f;  // (1/sqrt(64)) * log2(e)

    // glds pointers (per-lane; lane0 value is the wave-uniform LDS base)
    const char* kg = (const char*)Kz + (size_t)h * 64 * 8192 + wv * 2048 + ln * 16;
    const char* vg = (const char*)Vz + (size_t)h * 64 * 8192 + wv * 2048 + ln * 16;
    char* kl = (char*)smem + wv * 2048 + ln * 16;
    char* vl = (char*)smem + 24576 + wv * 2048 + ln * 16;

#define GLDS_TILE(IT, BUF) do {                                  \
    const char* ks_ = kg + (size_t)(IT) * 8192;                  \
    const char* vs_ = vg + (size_t)(IT) * 8192;                  \
    char* kd_ = kl + (BUF) * 8192;                               \
    char* vd_ = vl + (BUF) * 8192;                               \
    gl16(ks_, kd_); gl16(ks_ + 1024, kd_ + 1024);                \
    gl16(vs_, vd_); gl16(vs_ + 1024, vd_ + 1024);                \
} while (0)

    // start K/V tile 0/1 fetch immediately (overlaps with Q staging)
    GLDS_TILE(0, 0);
    GLDS_TILE(1, 1);

    // ---- stage Q tile (scaled fp32->bf16, swizzled) into K-buf2 overlay ----
    {
        const int r = tid >> 2, gg = tid & 3;
        const float* qp = Q + ((size_t)(q0 + r) * NH + h) * HD + 16 * gg;
        const float4 a = *reinterpret_cast<const float4*>(qp);
        const float4 b = *reinterpret_cast<const float4*>(qp + 4);
        const float4 c = *reinterpret_cast<const float4*>(qp + 8);
        const float4 d = *reinterpret_cast<const float4*>(qp + 12);
        uint4 f0, f1;
        f0.x = pkbf(a.x * SC, a.y * SC); f0.y = pkbf(a.z * SC, a.w * SC);
        f0.z = pkbf(b.x * SC, b.y * SC); f0.w = pkbf(b.z * SC, b.w * SC);
        f1.x = pkbf(c.x * SC, c.y * SC); f1.y = pkbf(c.z * SC, c.w * SC);
        f1.z = pkbf(d.x * SC, d.y * SC); f1.w = pkbf(d.z * SC, d.w * SC);
        unsigned short* out = Qlds + r * 64;
        *reinterpret_cast<uint4*>(out + (((2 * gg)     ^ (r & 7)) * 8)) = f0;
        *reinterpret_cast<uint4*>(out + (((2 * gg + 1) ^ (r & 7)) * 8)) = f1;
    }

    const int nIter = causal ? (x + 1) : (S_LEN / 64);

    floatx4 acc[4][2];   // [md (d-tile)][t_l (q-tile in wq half)], partial O^T over wk's kv
    #pragma unroll
    for (int m = 0; m < 4; ++m)
        #pragma unroll
        for (int t = 0; t < 2; ++t) acc[m][t] = floatx4{0.f, 0.f, 0.f, 0.f};
    float lacc[2] = {0.f, 0.f};

    const int e7 = c16 & 7;
    const int o0 = (qd ^ e7) * 8;              // elems, x32 frag chunk 0
    const int o1 = ((4 + qd) ^ e7) * 8;        // elems, x32 frag chunk 1
    // V^T b64 frag offsets for kv sub-tiles ks=0,1 of this wave's kv half
    const int vo0 = ((4 * wk + 0 + (qd >> 1)) ^ e7) * 8 + (qd & 1) * 4;
    const int vo1 = ((4 * wk + 2 + (qd >> 1)) ^ e7) * 8 + (qd & 1) * 4;

    __syncthreads();   // Q visible + tiles 0,1 landed (full drain; once per block)

    // ---- hoist loop-invariant Q fragments (this wave's 32 q rows, 16 VGPR) ----
    bf16x8 qh0[2], qh1[2];
    #pragma unroll
    for (int t = 0; t < 2; ++t) {
        const unsigned short* qrow = Qlds + (16 * (2 * wq + t) + c16) * 64;
        qh0[t] = *reinterpret_cast<const bf16x8*>(qrow + o0);
        qh1[t] = *reinterpret_cast<const bf16x8*>(qrow + o1);
    }
    __syncthreads();   // all waves done hoisting before iter-0 GLDS(2) hits buf2

    int br = 0;        // buffer holding tile it      (= it % 3)
    int b2 = 2;        // buffer for tile it+2        (= (it+2) % 3)
    for (int it = 0; it < nIter; ++it) {
        // tile `it` was issued >=2 iterations ago; tiles it+1 (4 loads) may
        // still be in flight -> counted wait keeps them flying.
        if (it == nIter - 1) {
            asm volatile("s_waitcnt vmcnt(0)" ::: "memory");
        } else {
            asm volatile("s_waitcnt vmcnt(4)" ::: "memory");
        }
        __builtin_amdgcn_s_barrier();

        if (it + 2 < nIter) GLDS_TILE(it + 2, b2);

        const unsigned short* Kb = Klds + br * 4096;
        const unsigned short* Vb = Vlds + br * 4096;

        // K fragments: this wave's kv half, two 16-row sub-tiles
        bf16x8 kf0[2], kf1[2];
        #pragma unroll
        for (int ks = 0; ks < 2; ++ks) {
            const unsigned short* krow = Kb + (32 * wk + 16 * ks + c16) * 64;
            kf0[ks] = *reinterpret_cast<const bf16x8*>(krow + o0);
            kf1[ks] = *reinterpret_cast<const bf16x8*>(krow + o1);
        }

        const bool maskit = (causal != 0) && (it == nIter - 1);

        // S^T = K Q^T per (ks, t); exp2 -> P in B-layout for x16 PV
        BF4 pf[2][2];   // [ks][t]
        #pragma unroll
        for (int ks = 0; ks < 2; ++ks) {
            const int kvb = 32 * wk + 16 * ks + 4 * qd;   // kv-local of reg i=0
            #pragma unroll
            for (int t = 0; t < 2; ++t) {
                floatx4 st = __builtin_amdgcn_mfma_f32_16x16x32_bf16(
                    kf0[ks], qh0[t], floatx4{0.f, 0.f, 0.f, 0.f}, 0, 0, 0);
                st = __builtin_amdgcn_mfma_f32_16x16x32_bf16(kf1[ks], qh1[t], st, 0, 0, 0);
                const int qloc = 16 * (2 * wq + t) + c16;
                float p[4];
                #pragma unroll
                for (int i = 0; i < 4; ++i) {
                    float sv = st[i];
                    if (maskit && (kvb + i > qloc)) sv = -1e30f;
                    p[i] = __builtin_amdgcn_exp2f(sv);
                }
                lacc[t] += (p[0] + p[1]) + (p[2] + p[3]);
                pf[ks][t].d[0] = pkbf(p[0], p[1]);
                pf[ks][t].d[1] = pkbf(p[2], p[3]);
            }
        }

        // O^T(partial) += V^T[:, kv_wk] P^T[kv_wk, :]  (x16, k=16 per sub-tile)
        #pragma unroll
        for (int md = 0; md < 4; ++md) {
            const unsigned short* vrow = Vb + (16 * md + c16) * 64;
            BF4 vf0, vf1;
            *reinterpret_cast<uint2*>(&vf0.d[0]) = *reinterpret_cast<const uint2*>(vrow + vo0);
            *reinterpret_cast<uint2*>(&vf1.d[0]) = *reinterpret_cast<const uint2*>(vrow + vo1);
            #pragma unroll
            for (int t = 0; t < 2; ++t) {
                acc[md][t] = mfma16(vf0.s, pf[0][t].s, acc[md][t]);
                acc[md][t] = mfma16(vf1.s, pf[1][t].s, acc[md][t]);
            }
        }

        br = (br == 2) ? 0 : br + 1;
        b2 = (b2 == 2) ? 0 : b2 + 1;
    }

    __syncthreads();   // all waves out of the K/V buffers before epilogue overlay

    // ---- epilogue: pairwise (wk=0 + wk=1) reduction via LDS ----
    // Lane (c16,qd) reg (md,t,i) holds O^T[d=16md+4qd+i][q=16(2wq+t)+c16] partial.
    #pragma unroll
    for (int t = 0; t < 2; ++t) {
        float lt = lacc[t];
        lt += __shfl_xor(lt, 16);
        lt += __shfl_xor(lt, 32);
        if (qd == 0) Lsum[wk * 64 + wq * 32 + t * 16 + c16] = lt;
    }
    if (wk == 0) {
        float* Lw = Lred + (wq * 64 + ln) * 36;
        #pragma unroll
        for (int md = 0; md < 4; ++md)
            #pragma unroll
            for (int t = 0; t < 2; ++t)
                *reinterpret_cast<floatx4*>(&Lw[(md * 2 + t) * 4]) = acc[md][t];
    }
    __syncthreads();
    if (wk == 1) {
        const float* Lr = Lred + (wq * 64 + ln) * 36;
        float inv[2];
        #pragma unroll
        for (int t = 0; t < 2; ++t) {
            const int qidx = wq * 32 + t * 16 + c16;
            inv[t] = 1.0f / (Lsum[qidx] + Lsum[64 + qidx]);
        }
        #pragma unroll
        for (int md = 0; md < 4; ++md)
            #pragma unroll
            for (int t = 0; t < 2; ++t) {
                const floatx4 b = *reinterpret_cast<const floatx4*>(&Lr[(md * 2 + t) * 4]);
                const floatx4 a = acc[md][t];
                floatx4 o;
                o[0] = (a[0] + b[0]) * inv[t];
                o[1] = (a[1] + b[1]) * inv[t];
                o[2] = (a[2] + b[2]) * inv[t];
                o[3] = (a[3] + b[3]) * inv[t];
                const int q = q0 + 16 * (2 * wq + t) + c16;
                *reinterpret_cast<floatx4*>(O + ((size_t)q * NH + h) * HD + 16 * md + 4 * qd) = o;
            }
    }
}

extern "C" void kernel_launch(void* const* d_in, const int* in_sizes, int n_in,
                              void* d_out, int out_size, void* d_ws, size_t ws_size,
                              hipStream_t stream) {
    const float* q = (const float*)d_in[0];
    const float* k = (const float*)d_in[1];
    const float* v = (const float*)d_in[2];
    const int* causal = (const int*)d_in[3];
    float* out = (float*)d_out;
    unsigned short* Kz = (unsigned short*)d_ws;                      // 8 MB
    unsigned short* Vz = Kz + (size_t)NH * 64 * 4096;                // 8 MB
    pp_kv<<<dim3(64 * NH), dim3(256), 0, stream>>>(k, v, Kz, Vz);
    fa_main<<<dim3(64 * NH), dim3(256), 0, stream>>>(q, Kz, Vz, causal, out);
}